// Round 6
// baseline (190.865 us; speedup 1.0000x reference)
//
#include <hip/hip_runtime.h>
#include <math.h>

#define BB 8
#define CC 64
#define OO 64
#define HH 128
#define WW 128
#define HW (HH*WW)              // 16384
#define NPIX (BB*HW)            // 131072

typedef __bf16 bf16x8 __attribute__((ext_vector_type(8)));
typedef float floatx4 __attribute__((ext_vector_type(4)));
typedef float f32x2  __attribute__((ext_vector_type(2)));
typedef unsigned short ushort_t;

// Workspace layout (bytes):
//  xt : bf16 NHWC [B][H][W][64]        16777216
//  wt : bf16 [64][576]  (o, tap*64+c)     73728
//  wb : bf16 [32][576]  (o27pad, tap*64+c) 36864
#define XT_BYTES  16777216
#define WT_BYTES  73728

__device__ __forceinline__ unsigned short f2b(float f) {
    unsigned u = __float_as_uint(f);
    u += 0x7fffu + ((u >> 16) & 1u);       // round-to-nearest-even
    return (unsigned short)(u >> 16);
}

// ---------------------------------------------------------------------------
// Kernel 1: NCHW fp32 -> NHWC bf16 transpose, packed 4B stores
// ---------------------------------------------------------------------------
__global__ __launch_bounds__(256) void transpose_kernel(
    const float* __restrict__ x, ushort_t* __restrict__ xt)
{
    __shared__ float tile[64][33];
    int bh = blockIdx.x;
    int w0 = blockIdx.y * 32;
    int b  = bh >> 7;
    int h  = bh & 127;
    int t  = threadIdx.x;
    int tx = t & 31;
    int ty = t >> 5;

    #pragma unroll
    for (int j = 0; j < 8; ++j) {
        int c = ty * 8 + j;
        tile[c][tx] = x[(((size_t)(b*CC + c))*HH + h)*WW + (w0 + tx)];
    }
    __syncthreads();
    #pragma unroll
    for (int j = 0; j < 4; ++j) {
        int w  = ty + 8*j;
        int cp = tx;
        unsigned u = (unsigned)f2b(tile[2*cp][w]) |
                     ((unsigned)f2b(tile[2*cp+1][w]) << 16);
        *(unsigned*)(xt + (((size_t)(b*HH + h))*WW + (w0 + w))*CC + 2*cp) = u;
    }
}

// ---------------------------------------------------------------------------
// Kernel 2: weight repack to bf16
// ---------------------------------------------------------------------------
__global__ __launch_bounds__(256) void repack_kernel(
    const float* __restrict__ wm, const float* __restrict__ woff,
    const float* __restrict__ wmask, ushort_t* __restrict__ wt,
    ushort_t* __restrict__ wb)
{
    int i = blockIdx.x * 256 + threadIdx.x;
    if (i < 36864) {
        int o = i / 576, k = i % 576, tap = k >> 6, c = k & 63;
        wt[i] = f2b(wm[o*576 + c*9 + tap]);
    }
    int j = i - 36864;
    if (j >= 0 && j < 18432) {
        int o = j / 576, k = j % 576, tap = k >> 6, c = k & 63;
        float v = 0.f;
        if (o < 18)      v = woff[o*576 + c*9 + tap];
        else if (o < 27) v = wmask[(o-18)*576 + c*9 + tap];
        wb[j] = f2b(v);
    }
}

// ---------------------------------------------------------------------------
// Kernel 3 (FUSED): per 8x8 tile:
//   1. stage 14x14 halo window (halo 3) of xt into LDS
//   2. conv3x3 -> 18 offsets + 9 sigmoid masks via MFMA -> om_lds (no HBM)
//   3. deformable bilinear sampling FROM LDS (global fallback if the corner
//      falls outside the window -- correctness holds for any offsets)
//   4. bf16 MFMA GEMM (M=64 px, N=64, K=576) -> out
// ---------------------------------------------------------------------------
#define WR 14                       // window rows/cols (8 + 2*3 halo)
#define WSTRIDE 72                  // shorts per window pixel (64 + pad)

__global__ __launch_bounds__(256) void fused_kernel(
    const ushort_t* __restrict__ xt, const ushort_t* __restrict__ wb,
    const float* __restrict__ boff, const float* __restrict__ bmsk,
    const ushort_t* __restrict__ wt, float* __restrict__ out)
{
    __shared__ ushort_t win[WR*WR*WSTRIDE];   // 28224 B
    __shared__ ushort_t samp[2*64*72];        // 18432 B
    __shared__ float    om_lds[64*28];        //  7168 B

    int t = threadIdx.x;
    int lane = t & 63, wv = t >> 6;
    int bid = blockIdx.x;
    int b  = bid >> 8;
    int th = (bid >> 4) & 15;
    int tw = bid & 15;
    int h0 = th * 8, w0 = tw * 8;
    const ushort_t* xbase = xt + ((size_t)b << 20);

    // ---- 1. stage 14x14 window, zero-padded outside the image ----
    for (int idx = t; idx < WR*WR*8; idx += 256) {
        int r   = idx / (WR*8);
        int rem = idx - r*(WR*8);
        int col = rem >> 3;
        int ch  = (rem & 7) << 3;
        int y = h0 + r - 3, x = w0 + col - 3;
        uint4 val = make_uint4(0,0,0,0);
        if ((unsigned)y < (unsigned)HH && (unsigned)x < (unsigned)WW)
            val = *(const uint4*)(xbase + (((y << 7) + x) << 6) + ch);
        *(uint4*)(win + (r*WR + col)*WSTRIDE + ch) = val;
    }
    __syncthreads();

    int n = lane & 15, quad = lane >> 4;

    // ---- 2. conv27: wave wv owns M-tile mt=wv (16 px), N=32, K=576 ----
    {
        const ushort_t* wb0 = wb + n*576;
        const ushort_t* wb1 = wb + (16 + n)*576;
        floatx4 acc0 = {0.f,0.f,0.f,0.f}, acc1 = {0.f,0.f,0.f,0.f};
        int trow = wv*2 + (n >> 3);          // tile row of pixel m=n
        int tcol = n & 7;

        #pragma unroll
        for (int s = 0; s < 18; ++s) {
            int tap  = s >> 1;
            int tr   = tap / 3, tc = tap % 3;
            int coff = (s & 1)*32 + quad*8;
            int kk = tap*64 + coff;
            bf16x8 b0 = *(const bf16x8*)(wb0 + kk);
            bf16x8 b1 = *(const bf16x8*)(wb1 + kk);
            bf16x8 a = *(const bf16x8*)(win +
                ((trow + tr + 2)*WR + (tcol + tc + 2))*WSTRIDE + coff);
            acc0 = __builtin_amdgcn_mfma_f32_16x16x32_bf16(a, b0, acc0, 0, 0, 0);
            acc1 = __builtin_amdgcn_mfma_f32_16x16x32_bf16(a, b1, acc1, 0, 0, 0);
        }

        // epilogue into om_lds: pixel p = wv*16 + quad*4 + r, channel n / 16+n
        #pragma unroll
        for (int r = 0; r < 4; ++r) {
            int p = wv*16 + quad*4 + r;
            float* dst = om_lds + p*28;
            dst[n] = acc0[r] + boff[n];
            int o1 = 16 + n;
            if (o1 < 18) {
                dst[o1] = acc1[r] + boff[o1];
            } else if (o1 < 27) {
                float z = acc1[r] + bmsk[o1 - 18];
                dst[o1] = 1.f / (1.f + expf(-z));
            }
        }
    }
    __syncthreads();

    // ---- 3+4. deform: phase-A role 4 thr/px (16 ch each) ----
    int pa = t >> 2, cg = t & 3;
    int ph = pa >> 3, pw = pa & 7;
    int h_a = h0 + ph, w_a = w0 + pw;
    const float* omp = om_lds + pa*28;

    floatx4 acc[4];
    #pragma unroll
    for (int i = 0; i < 4; ++i) acc[i] = (floatx4){0.f,0.f,0.f,0.f};
    const ushort_t* wrow = wt + (wv*16 + n)*576;

    for (int k = 0; k < 9; ++k) {
        ushort_t* sb = samp + (k & 1) * (64*72);

        int kr = k / 3, kc = k - kr*3;
        float dy = omp[2*k], dx = omp[2*k + 1], m = omp[18 + k];
        float py = (float)(h_a + kr - 1) + dy;
        float px = (float)(w_a + kc - 1) + dx;
        float y0f = floorf(py), x0f = floorf(px);
        float ly = py - y0f, lx = px - x0f;
        int y0 = (int)y0f, x0 = (int)x0f, y1 = y0 + 1, x1 = x0 + 1;
        float vy0 = ((unsigned)y0 < (unsigned)HH) ? 1.f : 0.f;
        float vy1 = ((unsigned)y1 < (unsigned)HH) ? 1.f : 0.f;
        float vx0 = ((unsigned)x0 < (unsigned)WW) ? 1.f : 0.f;
        float vx1 = ((unsigned)x1 < (unsigned)WW) ? 1.f : 0.f;

        float cw[4] = { (1.f-ly)*(1.f-lx)*vy0*vx0*m,
                        (1.f-ly)*lx      *vy0*vx1*m,
                        ly*(1.f-lx)      *vy1*vx0*m,
                        ly*lx            *vy1*vx1*m };
        int ys[4] = { y0, y0, y1, y1 };
        int xs[4] = { x0, x1, x0, x1 };

        f32x2 v2[8];
        #pragma unroll
        for (int i = 0; i < 8; ++i) v2[i] = (f32x2){0.f, 0.f};

        #pragma unroll
        for (int cn = 0; cn < 4; ++cn) {
            int yc = min(max(ys[cn], 0), HH-1);
            int xc = min(max(xs[cn], 0), WW-1);
            int wy = yc - h0 + 3, wx = xc - w0 + 3;
            uint4 q0, q1;
            if ((unsigned)wy < (unsigned)WR && (unsigned)wx < (unsigned)WR) {
                const uint4* cp = (const uint4*)(win + (wy*WR + wx)*WSTRIDE + cg*16);
                q0 = cp[0]; q1 = cp[1];
            } else {          // offset pushed corner outside the staged window
                const uint4* cp = (const uint4*)(xbase + (((yc << 7) + xc) << 6) + cg*16);
                q0 = cp[0]; q1 = cp[1];
            }
            unsigned d[8] = { q0.x, q0.y, q0.z, q0.w, q1.x, q1.y, q1.z, q1.w };
            float wg = cw[cn];
            #pragma unroll
            for (int j = 0; j < 8; ++j) {
                f32x2 e;
                e.x = __uint_as_float(d[j] << 16);
                e.y = __uint_as_float(d[j] & 0xffff0000u);
                v2[j] += e * wg;            // -> v_pk_fma_f32
            }
        }

        // pack 16 fp32 -> 16 bf16, 32B to sb[pa][cg*16..]
        {
            unsigned uu[8];
            #pragma unroll
            for (int j = 0; j < 8; ++j)
                uu[j] = (unsigned)f2b(v2[j].x) | ((unsigned)f2b(v2[j].y) << 16);
            uint4* dst = (uint4*)(sb + pa*72 + cg*16);
            dst[0] = make_uint4(uu[0], uu[1], uu[2], uu[3]);
            dst[1] = make_uint4(uu[4], uu[5], uu[6], uu[7]);
        }
        __syncthreads();

        // phase B: MFMA accumulate
        #pragma unroll
        for (int half = 0; half < 2; ++half) {
            bf16x8 bfrag = *(const bf16x8*)(wrow + k*64 + half*32 + quad*8);
            #pragma unroll
            for (int mt = 0; mt < 4; ++mt) {
                bf16x8 afrag = *(const bf16x8*)(sb + (mt*16 + n)*72 + half*32 + quad*8);
                acc[mt] = __builtin_amdgcn_mfma_f32_16x16x32_bf16(afrag, bfrag, acc[mt], 0, 0, 0);
            }
        }
        __syncthreads();
    }

    // store: out[b][o][h][w], o = wv*16 + n
    // p_local = mt*16 + quad*4 + r -> row = h0 + mt*2 + (quad>>1),
    //                                  col = w0 + (quad&1)*4 + r
    float* op = out + ((size_t)b*OO + (wv*16 + n))*HW;
    #pragma unroll
    for (int mt = 0; mt < 4; ++mt) {
        int row = h0 + mt*2 + (quad >> 1);
        int col = w0 + (quad & 1)*4;
        float4 st = make_float4(acc[mt][0], acc[mt][1], acc[mt][2], acc[mt][3]);
        *(float4*)(op + row*WW + col) = st;
    }
}

// ---------------------------------------------------------------------------
extern "C" void kernel_launch(void* const* d_in, const int* in_sizes, int n_in,
                              void* d_out, int out_size, void* d_ws, size_t ws_size,
                              hipStream_t stream)
{
    const float* x      = (const float*)d_in[0];
    const float* w_main = (const float*)d_in[1];
    const float* w_off  = (const float*)d_in[2];
    const float* b_off  = (const float*)d_in[3];
    const float* w_msk  = (const float*)d_in[4];
    const float* b_msk  = (const float*)d_in[5];
    float* out = (float*)d_out;

    unsigned char* ws = (unsigned char*)d_ws;
    ushort_t* xt = (ushort_t*)ws;
    ushort_t* wt = (ushort_t*)(ws + XT_BYTES);
    ushort_t* wb = (ushort_t*)(ws + XT_BYTES + WT_BYTES);

    dim3 tgrid(BB*HH, WW/32);
    transpose_kernel<<<tgrid, 256, 0, stream>>>(x, xt);

    repack_kernel<<<(36864 + 18432 + 255)/256, 256, 0, stream>>>(
        w_main, w_off, w_msk, wt, wb);

    fused_kernel<<<NPIX/64, 256, 0, stream>>>(xt, wb, b_off, b_msk, wt, out);
}

// Round 7
// 171.226 us; speedup vs baseline: 1.1147x; 1.1147x over previous
//
#include <hip/hip_runtime.h>
#include <math.h>

#define BB 8
#define CC 64
#define OO 64
#define HH 128
#define WW 128
#define HW (HH*WW)              // 16384
#define NPIX (BB*HW)            // 131072

typedef __bf16 bf16x8 __attribute__((ext_vector_type(8)));
typedef float floatx4 __attribute__((ext_vector_type(4)));
typedef float f32x2  __attribute__((ext_vector_type(2)));
typedef unsigned short ushort_t;

// Workspace layout (bytes):
//  xt : bf16 NHWC [B][H][W][64]        16777216
//  wt : bf16 [64][576]  (o, tap*64+c)     73728
//  wb : bf16 [32][576]  (o27pad, tap*64+c) 36864
#define XT_BYTES  16777216
#define WT_BYTES  73728

__device__ __forceinline__ unsigned short f2b(float f) {
    unsigned u = __float_as_uint(f);
    u += 0x7fffu + ((u >> 16) & 1u);       // round-to-nearest-even
    return (unsigned short)(u >> 16);
}

// ---------------------------------------------------------------------------
// Kernel 1: NCHW fp32 -> NHWC bf16 transpose. One block per (b,h) row.
// Read: float4, 512B contiguous per half-wave. Write: uint4 (8 packed bf16),
// 1KB contiguous per wave. LDS stride 129 floats (2-way max on reads).
// ---------------------------------------------------------------------------
__global__ __launch_bounds__(256) void transpose_kernel(
    const float* __restrict__ x, ushort_t* __restrict__ xt)
{
    __shared__ float tile[64*129];
    int bh = blockIdx.x;
    int b = bh >> 7, h = bh & 127;
    int t = threadIdx.x;

    const float* xrow = x + ((size_t)b*CC*HH + h)*WW;   // stride HW between c
    #pragma unroll
    for (int it = 0; it < 8; ++it) {
        int c = it*8 + (t >> 5);
        int w = (t & 31) * 4;
        float4 v = *(const float4*)(xrow + (size_t)c*HW + w);
        float* dst = tile + c*129 + w;
        dst[0] = v.x; dst[1] = v.y; dst[2] = v.z; dst[3] = v.w;
    }
    __syncthreads();
    ushort_t* orow = xt + (((size_t)(b*HH + h))*WW) * CC;
    #pragma unroll
    for (int it = 0; it < 4; ++it) {
        int w  = it*32 + (t >> 3);
        int cg = t & 7;
        unsigned uu[4];
        #pragma unroll
        for (int j = 0; j < 4; ++j) {
            float lo = tile[(cg*8 + 2*j)*129 + w];
            float hi = tile[(cg*8 + 2*j + 1)*129 + w];
            uu[j] = (unsigned)f2b(lo) | ((unsigned)f2b(hi) << 16);
        }
        *(uint4*)(orow + (size_t)w*CC + cg*8) = make_uint4(uu[0],uu[1],uu[2],uu[3]);
    }
}

// ---------------------------------------------------------------------------
// Kernel 2: weight repack to bf16
// ---------------------------------------------------------------------------
__global__ __launch_bounds__(256) void repack_kernel(
    const float* __restrict__ wm, const float* __restrict__ woff,
    const float* __restrict__ wmask, ushort_t* __restrict__ wt,
    ushort_t* __restrict__ wb)
{
    int i = blockIdx.x * 256 + threadIdx.x;
    if (i < 36864) {
        int o = i / 576, k = i % 576, tap = k >> 6, c = k & 63;
        wt[i] = f2b(wm[o*576 + c*9 + tap]);
    }
    int j = i - 36864;
    if (j >= 0 && j < 18432) {
        int o = j / 576, k = j % 576, tap = k >> 6, c = k & 63;
        float v = 0.f;
        if (o < 18)      v = woff[o*576 + c*9 + tap];
        else if (o < 27) v = wmask[(o-18)*576 + c*9 + tap];
        wb[j] = f2b(v);
    }
}

// ---------------------------------------------------------------------------
// Kernel 3 (FUSED): per 8x8 tile:
//   1. stage 12x12 halo window (halo 2) of xt into LDS
//   2. conv3x3 -> 18 offsets + 9 sigmoid masks via MFMA -> om_lds (no HBM)
//   3. deformable bilinear sampling from LDS (global fallback for far corners)
//      pipelined one tap ahead of 4. bf16 MFMA GEMM -> out
// LDS: win 20736 + samp 9216 + om 7424 = 37376 B -> 4 blocks/CU
// ---------------------------------------------------------------------------
#define WR 12                       // window rows/cols (8 + 2*2 halo)
#define WSTRIDE 72                  // shorts per window pixel (64 + pad)
#define OMS 29                      // om_lds floats per pixel (28 + pad)

__global__ __launch_bounds__(256) void fused_kernel(
    const ushort_t* __restrict__ xt, const ushort_t* __restrict__ wb,
    const float* __restrict__ boff, const float* __restrict__ bmsk,
    const ushort_t* __restrict__ wt, float* __restrict__ out)
{
    __shared__ ushort_t win[WR*WR*WSTRIDE];   // 20736 B
    __shared__ ushort_t samp[64*72];          //  9216 B
    __shared__ float    om_lds[64*OMS];       //  7424 B

    int t = threadIdx.x;
    int lane = t & 63, wv = t >> 6;
    int bid = blockIdx.x;
    int b  = bid >> 8;
    int th = (bid >> 4) & 15;
    int tw = bid & 15;
    int h0 = th * 8, w0 = tw * 8;
    const ushort_t* xbase = xt + ((size_t)b << 20);

    // ---- 1. stage 12x12 window, zero-padded outside the image ----
    for (int idx = t; idx < WR*WR*8; idx += 256) {
        int r   = idx / (WR*8);
        int rem = idx - r*(WR*8);
        int col = rem >> 3;
        int ch  = (rem & 7) << 3;
        int y = h0 + r - 2, x = w0 + col - 2;
        uint4 val = make_uint4(0,0,0,0);
        if ((unsigned)y < (unsigned)HH && (unsigned)x < (unsigned)WW)
            val = *(const uint4*)(xbase + (((y << 7) + x) << 6) + ch);
        *(uint4*)(win + (r*WR + col)*WSTRIDE + ch) = val;
    }
    __syncthreads();

    int n = lane & 15, quad = lane >> 4;

    // ---- 2. conv27: wave wv owns M-tile of 16 px, N=32, K=576 ----
    {
        const ushort_t* wb0 = wb + n*576;
        const ushort_t* wb1 = wb + (16 + n)*576;
        floatx4 acc0 = {0.f,0.f,0.f,0.f}, acc1 = {0.f,0.f,0.f,0.f};
        int trow = wv*2 + (n >> 3);          // tile row of pixel m=n
        int tcol = n & 7;

        #pragma unroll
        for (int s = 0; s < 18; ++s) {
            int tap  = s >> 1;
            int tr   = tap / 3, tc = tap % 3;
            int coff = (s & 1)*32 + quad*8;
            int kk = tap*64 + coff;
            bf16x8 b0 = *(const bf16x8*)(wb0 + kk);
            bf16x8 b1 = *(const bf16x8*)(wb1 + kk);
            bf16x8 a = *(const bf16x8*)(win +
                ((trow + tr + 1)*WR + (tcol + tc + 1))*WSTRIDE + coff);
            acc0 = __builtin_amdgcn_mfma_f32_16x16x32_bf16(a, b0, acc0, 0, 0, 0);
            acc1 = __builtin_amdgcn_mfma_f32_16x16x32_bf16(a, b1, acc1, 0, 0, 0);
        }

        // epilogue into om_lds: pixel p = wv*16 + quad*4 + r, channel n / 16+n
        #pragma unroll
        for (int r = 0; r < 4; ++r) {
            int p = wv*16 + quad*4 + r;
            float* dst = om_lds + p*OMS;
            dst[n] = acc0[r] + boff[n];
            int o1 = 16 + n;
            if (o1 < 18) {
                dst[o1] = acc1[r] + boff[o1];
            } else if (o1 < 27) {
                float z = acc1[r] + bmsk[o1 - 18];
                dst[o1] = 1.f / (1.f + expf(-z));
            }
        }
    }
    __syncthreads();

    // ---- 3+4. deform: phase-A role 4 thr/px (16 ch each), pipelined ----
    int pa = t >> 2, cg = t & 3;
    int ph = pa >> 3, pw = pa & 7;
    int h_a = h0 + ph, w_a = w0 + pw;
    const float* omp = om_lds + pa*OMS;

    floatx4 acc[4];
    #pragma unroll
    for (int i = 0; i < 4; ++i) acc[i] = (floatx4){0.f,0.f,0.f,0.f};
    const ushort_t* wrow = wt + (wv*16 + n)*576;

    // phase A for tap k: reads only win/om_lds (stable) -> no samp dependence
    auto computeA = [&](int k, f32x2* v2) {
        int kr = k / 3, kc = k - kr*3;
        float dy = omp[2*k], dx = omp[2*k + 1], m = omp[18 + k];
        float py = (float)(h_a + kr - 1) + dy;
        float px = (float)(w_a + kc - 1) + dx;
        float y0f = floorf(py), x0f = floorf(px);
        float ly = py - y0f, lx = px - x0f;
        int y0 = (int)y0f, x0 = (int)x0f, y1 = y0 + 1, x1 = x0 + 1;
        float vy0 = ((unsigned)y0 < (unsigned)HH) ? 1.f : 0.f;
        float vy1 = ((unsigned)y1 < (unsigned)HH) ? 1.f : 0.f;
        float vx0 = ((unsigned)x0 < (unsigned)WW) ? 1.f : 0.f;
        float vx1 = ((unsigned)x1 < (unsigned)WW) ? 1.f : 0.f;

        float cw[4] = { (1.f-ly)*(1.f-lx)*vy0*vx0*m,
                        (1.f-ly)*lx      *vy0*vx1*m,
                        ly*(1.f-lx)      *vy1*vx0*m,
                        ly*lx            *vy1*vx1*m };
        int ys[4] = { y0, y0, y1, y1 };
        int xs[4] = { x0, x1, x0, x1 };

        #pragma unroll
        for (int i = 0; i < 8; ++i) v2[i] = (f32x2){0.f, 0.f};

        #pragma unroll
        for (int cn = 0; cn < 4; ++cn) {
            int yc = min(max(ys[cn], 0), HH-1);
            int xc = min(max(xs[cn], 0), WW-1);
            int wy = yc - h0 + 2, wx = xc - w0 + 2;
            uint4 q0, q1;
            if ((unsigned)wy < (unsigned)WR && (unsigned)wx < (unsigned)WR) {
                const uint4* cp = (const uint4*)(win + (wy*WR + wx)*WSTRIDE + cg*16);
                q0 = cp[0]; q1 = cp[1];
            } else {      // offset pushed corner outside the staged window
                const uint4* cp = (const uint4*)(xbase + (((yc << 7) + xc) << 6) + cg*16);
                q0 = cp[0]; q1 = cp[1];
            }
            unsigned d[8] = { q0.x, q0.y, q0.z, q0.w, q1.x, q1.y, q1.z, q1.w };
            float wg = cw[cn];
            #pragma unroll
            for (int j = 0; j < 8; ++j) {
                f32x2 e;
                e.x = __uint_as_float(d[j] << 16);
                e.y = __uint_as_float(d[j] & 0xffff0000u);
                v2[j] += e * wg;            // -> v_pk_fma_f32
            }
        }
    };

    f32x2 v2[8];
    computeA(0, v2);

    for (int k = 0; k < 9; ++k) {
        // write samp <- v2 (previous readers of samp finished at the barrier
        // that ended iteration k-1, or the post-conv barrier for k=0)
        {
            unsigned uu[8];
            #pragma unroll
            for (int j = 0; j < 8; ++j)
                uu[j] = (unsigned)f2b(v2[j].x) | ((unsigned)f2b(v2[j].y) << 16);
            uint4* dst = (uint4*)(samp + pa*72 + cg*16);
            dst[0] = make_uint4(uu[0], uu[1], uu[2], uu[3]);
            dst[1] = make_uint4(uu[4], uu[5], uu[6], uu[7]);
        }
        __syncthreads();   // publish samp for tap k

        // phase B (MFMA on samp) + phase A for tap k+1 — independent, can
        // co-issue on the MFMA and VALU pipes
        #pragma unroll
        for (int half = 0; half < 2; ++half) {
            bf16x8 bfrag = *(const bf16x8*)(wrow + k*64 + half*32 + quad*8);
            #pragma unroll
            for (int mt = 0; mt < 4; ++mt) {
                bf16x8 afrag = *(const bf16x8*)(samp + (mt*16 + n)*72 + half*32 + quad*8);
                acc[mt] = __builtin_amdgcn_mfma_f32_16x16x32_bf16(afrag, bfrag, acc[mt], 0, 0, 0);
            }
        }
        if (k < 8) computeA(k + 1, v2);

        __syncthreads();   // all reads of samp done before next write
    }

    // store: out[b][o][h][w], o = wv*16 + n
    // p_local = mt*16 + quad*4 + r -> row = h0 + mt*2 + (quad>>1),
    //                                  col = w0 + (quad&1)*4 + r
    float* op = out + ((size_t)b*OO + (wv*16 + n))*HW;
    #pragma unroll
    for (int mt = 0; mt < 4; ++mt) {
        int row = h0 + mt*2 + (quad >> 1);
        int col = w0 + (quad & 1)*4;
        float4 st = make_float4(acc[mt][0], acc[mt][1], acc[mt][2], acc[mt][3]);
        *(float4*)(op + row*WW + col) = st;
    }
}

// ---------------------------------------------------------------------------
extern "C" void kernel_launch(void* const* d_in, const int* in_sizes, int n_in,
                              void* d_out, int out_size, void* d_ws, size_t ws_size,
                              hipStream_t stream)
{
    const float* x      = (const float*)d_in[0];
    const float* w_main = (const float*)d_in[1];
    const float* w_off  = (const float*)d_in[2];
    const float* b_off  = (const float*)d_in[3];
    const float* w_msk  = (const float*)d_in[4];
    const float* b_msk  = (const float*)d_in[5];
    float* out = (float*)d_out;

    unsigned char* ws = (unsigned char*)d_ws;
    ushort_t* xt = (ushort_t*)ws;
    ushort_t* wt = (ushort_t*)(ws + XT_BYTES);
    ushort_t* wb = (ushort_t*)(ws + XT_BYTES + WT_BYTES);

    transpose_kernel<<<BB*HH, 256, 0, stream>>>(x, xt);

    repack_kernel<<<(36864 + 18432 + 255)/256, 256, 0, stream>>>(
        w_main, w_off, w_msk, wt, wb);

    fused_kernel<<<NPIX/64, 256, 0, stream>>>(xt, wb, b_off, b_msk, wt, out);
}